// Round 3
// baseline (222.768 us; speedup 1.0000x reference)
//
#include <hip/hip_runtime.h>
#include <hip/hip_cooperative_groups.h>

namespace cg = cooperative_groups;

#define N 1024
#define E 256
#define H 128
#define QSTR 136  // halves; 272 B row stride -> conflict-free b128

typedef _Float16 hv2 __attribute__((ext_vector_type(2)));
typedef _Float16 half_t;

__device__ __forceinline__ float dot2_acc(hv2 a, hv2 b, float c) {
#if __has_builtin(__builtin_amdgcn_fdot2)
    return __builtin_amdgcn_fdot2(a, b, c, false);
#else
    return c + (float)a.x * (float)b.x + (float)a.y * (float)b.y;
#endif
}

__device__ __forceinline__ hv2 relu_add2(hv2 a, hv2 b) {
    hv2 s = a + b;
    hv2 z = (hv2)(_Float16)0.f;
    return __builtin_elementwise_max(s, z);
}

// One cooperative kernel, 3 phases separated by grid.sync():
//  phase 1 (blocks 0..256):  Wq'=Wq@W1a, Wk'=Wk@W1b rows; block 256: ctx+consts
//  phase 2 (blocks 0..511):  q/k projection, 2 rows each, f16 out
//  phase 3 (all 528 blocks): one 32x32 upper-tri pair tile each
// LDS: pair-phase arrays, aliased as float scratch in phases 1-2.
// __launch_bounds__(256,3): >=3 blocks/CU co-resident (768 >= 528) so the
// cooperative launch validates; LDS 17.7 KB allows 9 blocks/CU.
__global__ __launch_bounds__(256, 3) void fused_kernel(
    const float* __restrict__ x, const float* __restrict__ P,
    const float* __restrict__ Wq, const float* __restrict__ bq,
    const float* __restrict__ Wk, const float* __restrict__ bk,
    const float* __restrict__ Wc, const float* __restrict__ bc,
    const float* __restrict__ W1, const float* __restrict__ b1,
    const float* __restrict__ W2, const float* __restrict__ b2,
    float* __restrict__ Wqp, float* __restrict__ Wkp,
    float* __restrict__ constq, float* __restrict__ constk,
    half_t* __restrict__ qh, half_t* __restrict__ kh,
    float* __restrict__ out) {
    cg::grid_group grid = cg::this_grid();

    __shared__ __align__(16) half_t qs[32][QSTR];
    __shared__ __align__(16) half_t ks[32][QSTR];
    __shared__ __align__(16) half_t w2s[H];
    float* fs = (float*)&qs[0][0];  // 2176-float scratch alias (phases 1-2)

    int b = blockIdx.x;
    int t = threadIdx.x;

    // ---------------- phase 1: weight fold + context ----------------
    if (b < E) {
        float* wq_s = fs;
        float* wk_s = fs + H;
        if (t < H) wq_s[t] = Wq[b * H + t];
        else       wk_s[t - H] = Wk[b * H + (t - H)];
        __syncthreads();
        int h = t & (H - 1);
        float acc = 0.f;
        if (t < H) {
#pragma unroll 8
            for (int r = 0; r < H; ++r) acc += wq_s[r] * W1[r * H + h];
            Wqp[b * H + h] = acc;
        } else {
#pragma unroll 8
            for (int r = 0; r < H; ++r) acc += wk_s[r] * W1[(H + r) * H + h];
            Wkp[b * H + h] = acc;
        }
    } else if (b == E) {
        float* xs   = fs;              // E floats
        float* pc   = fs + E;          // 2*H floats
        float* aq_s = fs + E + 2 * H;  // H floats
        float* ak_s = fs + E + 3 * H;  // H floats
        xs[t] = x[t];
        __syncthreads();
        int h = t & (H - 1);
        int c = t >> 7;  // 0 or 1
        float p = 0.f;
#pragma unroll 8
        for (int e = c * H; e < c * H + H; ++e) p += xs[e] * Wc[e * H + h];
        pc[c * H + h] = p;
        __syncthreads();
        if (t < H) {
            float ctxv = fmaxf(pc[t] + pc[H + t] + bc[t], 0.f);
            aq_s[t] = bq[t] + ctxv;
            ak_s[t] = bk[t] + ctxv;
        }
        __syncthreads();
        if (t < H) {
            float acc = b1[h];
#pragma unroll 8
            for (int r = 0; r < H; ++r) acc += aq_s[r] * W1[r * H + h];
            constq[h] = acc;
        } else {
            float acc = 0.f;
#pragma unroll 8
            for (int r = 0; r < H; ++r) acc += ak_s[r] * W1[(H + r) * H + h];
            constk[h] = acc;
        }
    }

    grid.sync();

    // ---------------- phase 2: projection (2 rows/block) ----------------
    if (b < N / 2) {
        float* p_s = fs;  // 2*E floats
        int i0 = b * 2;
        if (t < 128) ((float4*)p_s)[t] = ((const float4*)(P + i0 * E))[t];
        __syncthreads();
        bool isq = t < H;
        int h = t & (H - 1);
        const float* M = isq ? Wqp : Wkp;
        float cv = isq ? constq[h] : constk[h];
        float a0 = cv, a1 = cv;
        for (int e = 0; e < E; e += 8) {
            float m0 = M[(e + 0) * H + h];
            float m1 = M[(e + 1) * H + h];
            float m2 = M[(e + 2) * H + h];
            float m3 = M[(e + 3) * H + h];
            float m4 = M[(e + 4) * H + h];
            float m5 = M[(e + 5) * H + h];
            float m6 = M[(e + 6) * H + h];
            float m7 = M[(e + 7) * H + h];
            float4 p0a = *(const float4*)&p_s[0 * E + e];
            float4 p0b = *(const float4*)&p_s[0 * E + e + 4];
            float4 p1a = *(const float4*)&p_s[1 * E + e];
            float4 p1b = *(const float4*)&p_s[1 * E + e + 4];
            a0 += p0a.x * m0 + p0a.y * m1 + p0a.z * m2 + p0a.w * m3
                + p0b.x * m4 + p0b.y * m5 + p0b.z * m6 + p0b.w * m7;
            a1 += p1a.x * m0 + p1a.y * m1 + p1a.z * m2 + p1a.w * m3
                + p1b.x * m4 + p1b.y * m5 + p1b.z * m6 + p1b.w * m7;
        }
        half_t* O = isq ? qh : kh;
        O[(i0 + 0) * H + h] = (half_t)a0;
        O[(i0 + 1) * H + h] = (half_t)a1;
    }

    grid.sync();

    // ---------------- phase 3: pair tiles ----------------
    {
        int tid = b;
        int bi = (int)((65.0f - sqrtf(4225.0f - 8.0f * (float)tid)) * 0.5f);
        while (bi > 0 && tid < 32 * bi - bi * (bi - 1) / 2) --bi;
        while (tid >= 32 * (bi + 1) - (bi + 1) * bi / 2) ++bi;
        int bj = bi + (tid - (32 * bi - bi * (bi - 1) / 2));

        if (t < H) w2s[t] = (half_t)W2[t];

        const float4* qh4 = (const float4*)(qh + bi * 32 * H);
        const float4* kh4 = (const float4*)(kh + bj * 32 * H);
#pragma unroll
        for (int v = 0; v < 2; ++v) {
            int idx = v * 256 + t;  // 0..511 : 32 rows x 16 float4
            int r = idx >> 4, c = idx & 15;
            float4 q = qh4[idx];
            float4 k = kh4[idx];
            *(float4*)&qs[r][c * 8] = q;
            *(float4*)&ks[r][c * 8] = k;
        }
        __syncthreads();

        int jj  = t & 31;  // k row within tile
        int ti0 = t >> 5;  // q rows ti0, ti0+8, ti0+16, ti0+24
        float b2v = b2[0];
        float acc[4];
#pragma unroll
        for (int u = 0; u < 4; ++u) acc[u] = b2v;

        for (int h8 = 0; h8 < 16; ++h8) {
            float4 wf = *(const float4*)&w2s[h8 * 8];
            float4 kv = *(const float4*)&ks[jj][h8 * 8];
            const hv2* wp = (const hv2*)&wf;
            const hv2* kp2 = (const hv2*)&kv;
#pragma unroll
            for (int u = 0; u < 4; ++u) {
                float4 qf = *(const float4*)&qs[ti0 + u * 8][h8 * 8];
                const hv2* qp2 = (const hv2*)&qf;
#pragma unroll
                for (int s = 0; s < 4; ++s) {
                    hv2 sa = relu_add2(qp2[s], kp2[s]);
                    acc[u] = dot2_acc(sa, wp[s], acc[u]);
                }
            }
        }

#pragma unroll
        for (int u = 0; u < 4; ++u) {
            int i = bi * 32 + ti0 + u * 8;
            int j = bj * 32 + jj;
            if (j > i) {
                int base = i * (2 * N - i - 1) / 2;
                out[base + (j - i - 1)] = acc[u];
            }
        }
    }
}

extern "C" void kernel_launch(void* const* d_in, const int* in_sizes, int n_in,
                              void* d_out, int out_size, void* d_ws, size_t ws_size,
                              hipStream_t stream) {
    const float* x  = (const float*)d_in[0];
    const float* P  = (const float*)d_in[1];
    const float* Wq = (const float*)d_in[2];
    const float* bq = (const float*)d_in[3];
    const float* Wk = (const float*)d_in[4];
    const float* bk = (const float*)d_in[5];
    const float* Wc = (const float*)d_in[6];
    const float* bc = (const float*)d_in[7];
    const float* W1 = (const float*)d_in[8];
    const float* b1 = (const float*)d_in[9];
    const float* W2 = (const float*)d_in[10];
    const float* b2 = (const float*)d_in[11];
    float* out = (float*)d_out;

    float* ws     = (float*)d_ws;
    float* constq = ws;                      // 128
    float* constk = ws + H;                  // 128
    float* Wqp    = ws + 2 * H;              // 256*128
    float* Wkp    = Wqp + E * H;             // 256*128
    half_t* qh    = (half_t*)(Wkp + E * H);  // 1024*128 halves
    half_t* kh    = qh + N * H;              // 1024*128 halves

    void* args[] = {
        (void*)&x,  (void*)&P,  (void*)&Wq, (void*)&bq, (void*)&Wk, (void*)&bk,
        (void*)&Wc, (void*)&bc, (void*)&W1, (void*)&b1, (void*)&W2, (void*)&b2,
        (void*)&Wqp, (void*)&Wkp, (void*)&constq, (void*)&constk,
        (void*)&qh, (void*)&kh, (void*)&out};
    hipLaunchCooperativeKernel((const void*)fused_kernel, dim3(528), dim3(256),
                               args, 0, stream);
}

// Round 4
// 201.734 us; speedup vs baseline: 1.1043x; 1.1043x over previous
//
#include <hip/hip_runtime.h>
#include <hip/hip_cooperative_groups.h>

#define N 1024
#define E 256
#define H 128
#define NBLK 528
#define QSTR 136  // halves; 272 B row stride -> conflict-free b128

typedef _Float16 hv2 __attribute__((ext_vector_type(2)));
typedef _Float16 half_t;

__device__ __forceinline__ float dot2_acc(hv2 a, hv2 b, float c) {
#if __has_builtin(__builtin_amdgcn_fdot2)
    return __builtin_amdgcn_fdot2(a, b, c, false);
#else
    return c + (float)a.x * (float)b.x + (float)a.y * (float)b.y;
#endif
}

__device__ __forceinline__ hv2 relu_add2(hv2 a, hv2 b) {
    hv2 s = a + b;
    hv2 z = (hv2)(_Float16)0.f;
    return __builtin_elementwise_max(s, z);
}

// Lightweight device-scope grid barrier (replaces cg::grid.sync(), which uses
// a sleep-backoff spin measured at ~50 us/sync on this 8-XCD chip).
// One {cnt,flag} pair per barrier instance, zeroed by hipMemsetAsync pre-launch.
// thread 0: release fence (L2 wb) -> arrive -> relaxed agent poll (each poll is
// one coherence-point round trip, no s_sleep) -> acquire fence (L1/L2 inv).
__device__ __forceinline__ void grid_barrier(int* cnt, int* flag) {
    __syncthreads();  // drains each wave's vmem (stores visible to L2)
    if (threadIdx.x == 0) {
        __threadfence();  // release: XCD L2 writeback -> writes device-visible
        if (atomicAdd(cnt, 1) == NBLK - 1) {
            __hip_atomic_store(flag, 1, __ATOMIC_RELEASE, __HIP_MEMORY_SCOPE_AGENT);
        } else {
            while (__hip_atomic_load(flag, __ATOMIC_RELAXED, __HIP_MEMORY_SCOPE_AGENT) == 0) {}
        }
        __threadfence();  // acquire: invalidate this CU's L1 + XCD L2
    }
    __syncthreads();
}

// One cooperative kernel, 3 phases separated by custom grid barriers:
//  phase 1 (blocks 0..256):  Wq'=Wq@W1a, Wk'=Wk@W1b rows; block 256: ctx+consts
//  phase 2 (blocks 0..511):  q/k projection, 2 rows each, f16 out
//  phase 3 (all 528 blocks): one 32x32 upper-tri pair tile each
__global__ __launch_bounds__(256, 3) void fused_kernel(
    const float* __restrict__ x, const float* __restrict__ P,
    const float* __restrict__ Wq, const float* __restrict__ bq,
    const float* __restrict__ Wk, const float* __restrict__ bk,
    const float* __restrict__ Wc, const float* __restrict__ bc,
    const float* __restrict__ W1, const float* __restrict__ b1,
    const float* __restrict__ W2, const float* __restrict__ b2,
    int* bar,
    float* __restrict__ Wqp, float* __restrict__ Wkp,
    float* __restrict__ constq, float* __restrict__ constk,
    half_t* __restrict__ qh, half_t* __restrict__ kh,
    float* __restrict__ out) {
    __shared__ __align__(16) half_t qs[32][QSTR];
    __shared__ __align__(16) half_t ks[32][QSTR];
    __shared__ __align__(16) half_t w2s[H];
    float* fs = (float*)&qs[0][0];  // float scratch alias (phases 1-2)

    int b = blockIdx.x;
    int t = threadIdx.x;

    // ---------------- phase 1: weight fold + context ----------------
    if (b < E) {
        float* wq_s = fs;
        float* wk_s = fs + H;
        if (t < H) wq_s[t] = Wq[b * H + t];
        else       wk_s[t - H] = Wk[b * H + (t - H)];
        __syncthreads();
        int h = t & (H - 1);
        float acc = 0.f;
        if (t < H) {
#pragma unroll 8
            for (int r = 0; r < H; ++r) acc += wq_s[r] * W1[r * H + h];
            Wqp[b * H + h] = acc;
        } else {
#pragma unroll 8
            for (int r = 0; r < H; ++r) acc += wk_s[r] * W1[(H + r) * H + h];
            Wkp[b * H + h] = acc;
        }
    } else if (b == E) {
        float* xs   = fs;              // E floats
        float* pc   = fs + E;          // 2*H floats
        float* aq_s = fs + E + 2 * H;  // H floats
        float* ak_s = fs + E + 3 * H;  // H floats
        xs[t] = x[t];
        __syncthreads();
        int h = t & (H - 1);
        int c = t >> 7;  // 0 or 1
        float p = 0.f;
#pragma unroll 8
        for (int e = c * H; e < c * H + H; ++e) p += xs[e] * Wc[e * H + h];
        pc[c * H + h] = p;
        __syncthreads();
        if (t < H) {
            float ctxv = fmaxf(pc[t] + pc[H + t] + bc[t], 0.f);
            aq_s[t] = bq[t] + ctxv;
            ak_s[t] = bk[t] + ctxv;
        }
        __syncthreads();
        if (t < H) {
            float acc = b1[h];
#pragma unroll 8
            for (int r = 0; r < H; ++r) acc += aq_s[r] * W1[r * H + h];
            constq[h] = acc;
        } else {
            float acc = 0.f;
#pragma unroll 8
            for (int r = 0; r < H; ++r) acc += ak_s[r] * W1[(H + r) * H + h];
            constk[h] = acc;
        }
    }

    grid_barrier(bar + 0, bar + 1);

    // ---------------- phase 2: projection (2 rows/block) ----------------
    if (b < N / 2) {
        float* p_s = fs;  // 2*E floats
        int i0 = b * 2;
        if (t < 128) ((float4*)p_s)[t] = ((const float4*)(P + i0 * E))[t];
        __syncthreads();
        bool isq = t < H;
        int h = t & (H - 1);
        const float* M = isq ? Wqp : Wkp;
        float cv = isq ? constq[h] : constk[h];
        float a0 = cv, a1 = cv;
        for (int e = 0; e < E; e += 8) {
            float m0 = M[(e + 0) * H + h];
            float m1 = M[(e + 1) * H + h];
            float m2 = M[(e + 2) * H + h];
            float m3 = M[(e + 3) * H + h];
            float m4 = M[(e + 4) * H + h];
            float m5 = M[(e + 5) * H + h];
            float m6 = M[(e + 6) * H + h];
            float m7 = M[(e + 7) * H + h];
            float4 p0a = *(const float4*)&p_s[0 * E + e];
            float4 p0b = *(const float4*)&p_s[0 * E + e + 4];
            float4 p1a = *(const float4*)&p_s[1 * E + e];
            float4 p1b = *(const float4*)&p_s[1 * E + e + 4];
            a0 += p0a.x * m0 + p0a.y * m1 + p0a.z * m2 + p0a.w * m3
                + p0b.x * m4 + p0b.y * m5 + p0b.z * m6 + p0b.w * m7;
            a1 += p1a.x * m0 + p1a.y * m1 + p1a.z * m2 + p1a.w * m3
                + p1b.x * m4 + p1b.y * m5 + p1b.z * m6 + p1b.w * m7;
        }
        half_t* O = isq ? qh : kh;
        O[(i0 + 0) * H + h] = (half_t)a0;
        O[(i0 + 1) * H + h] = (half_t)a1;
    }

    grid_barrier(bar + 2, bar + 3);

    // ---------------- phase 3: pair tiles ----------------
    {
        int tid = b;
        int bi = (int)((65.0f - sqrtf(4225.0f - 8.0f * (float)tid)) * 0.5f);
        while (bi > 0 && tid < 32 * bi - bi * (bi - 1) / 2) --bi;
        while (tid >= 32 * (bi + 1) - (bi + 1) * bi / 2) ++bi;
        int bj = bi + (tid - (32 * bi - bi * (bi - 1) / 2));

        if (t < H) w2s[t] = (half_t)W2[t];

        const float4* qh4 = (const float4*)(qh + bi * 32 * H);
        const float4* kh4 = (const float4*)(kh + bj * 32 * H);
#pragma unroll
        for (int v = 0; v < 2; ++v) {
            int idx = v * 256 + t;  // 0..511 : 32 rows x 16 float4
            int r = idx >> 4, c = idx & 15;
            float4 q = qh4[idx];
            float4 k = kh4[idx];
            *(float4*)&qs[r][c * 8] = q;
            *(float4*)&ks[r][c * 8] = k;
        }
        __syncthreads();

        int jj  = t & 31;  // k row within tile
        int ti0 = t >> 5;  // q rows ti0, ti0+8, ti0+16, ti0+24
        float b2v = b2[0];
        float acc[4];
#pragma unroll
        for (int u = 0; u < 4; ++u) acc[u] = b2v;

        for (int h8 = 0; h8 < 16; ++h8) {
            float4 wf = *(const float4*)&w2s[h8 * 8];
            float4 kv = *(const float4*)&ks[jj][h8 * 8];
            const hv2* wp = (const hv2*)&wf;
            const hv2* kp2 = (const hv2*)&kv;
#pragma unroll
            for (int u = 0; u < 4; ++u) {
                float4 qf = *(const float4*)&qs[ti0 + u * 8][h8 * 8];
                const hv2* qp2 = (const hv2*)&qf;
#pragma unroll
                for (int s = 0; s < 4; ++s) {
                    hv2 sa = relu_add2(qp2[s], kp2[s]);
                    acc[u] = dot2_acc(sa, wp[s], acc[u]);
                }
            }
        }

#pragma unroll
        for (int u = 0; u < 4; ++u) {
            int i = bi * 32 + ti0 + u * 8;
            int j = bj * 32 + jj;
            if (j > i) {
                int base = i * (2 * N - i - 1) / 2;
                out[base + (j - i - 1)] = acc[u];
            }
        }
    }
}

extern "C" void kernel_launch(void* const* d_in, const int* in_sizes, int n_in,
                              void* d_out, int out_size, void* d_ws, size_t ws_size,
                              hipStream_t stream) {
    const float* x  = (const float*)d_in[0];
    const float* P  = (const float*)d_in[1];
    const float* Wq = (const float*)d_in[2];
    const float* bq = (const float*)d_in[3];
    const float* Wk = (const float*)d_in[4];
    const float* bk = (const float*)d_in[5];
    const float* Wc = (const float*)d_in[6];
    const float* bc = (const float*)d_in[7];
    const float* W1 = (const float*)d_in[8];
    const float* b1 = (const float*)d_in[9];
    const float* W2 = (const float*)d_in[10];
    const float* b2 = (const float*)d_in[11];
    float* out = (float*)d_out;

    float* ws     = (float*)d_ws;
    int* bar      = (int*)d_ws;              // 4 ints used; 256 B reserved
    float* constq = ws + 64;                 // 128
    float* constk = ws + 64 + H;             // 128
    float* Wqp    = ws + 64 + 2 * H;         // 256*128
    float* Wkp    = Wqp + E * H;             // 256*128
    half_t* qh    = (half_t*)(Wkp + E * H);  // 1024*128 halves
    half_t* kh    = qh + N * H;              // 1024*128 halves

    hipMemsetAsync(d_ws, 0, 256, stream);  // zero barrier state (ws is poisoned)

    void* args[] = {
        (void*)&x,  (void*)&P,  (void*)&Wq, (void*)&bq, (void*)&Wk, (void*)&bk,
        (void*)&Wc, (void*)&bc, (void*)&W1, (void*)&b1, (void*)&W2, (void*)&b2,
        (void*)&bar,
        (void*)&Wqp, (void*)&Wkp, (void*)&constq, (void*)&constk,
        (void*)&qh, (void*)&kh, (void*)&out};
    hipLaunchCooperativeKernel((const void*)fused_kernel, dim3(528), dim3(256),
                               args, 0, stream);
}

// Round 5
// 99.270 us; speedup vs baseline: 2.2441x; 2.0322x over previous
//
#include <hip/hip_runtime.h>

#define N 1024
#define E 256
#define H 128

typedef _Float16 hv2 __attribute__((ext_vector_type(2)));
typedef _Float16 half_t;

__device__ __forceinline__ float dot2_acc(hv2 a, hv2 b, float c) {
#if __has_builtin(__builtin_amdgcn_fdot2)
    return __builtin_amdgcn_fdot2(a, b, c, false);
#else
    return c + (float)a.x * (float)b.x + (float)a.y * (float)b.y;
#endif
}

__device__ __forceinline__ hv2 relu_add2(hv2 a, hv2 b) {
    hv2 s = a + b;
    hv2 z = (hv2)(_Float16)0.f;
    return __builtin_elementwise_max(s, z);
}

// proj (unfolded, self-contained — no setup kernel, no grid sync):
// per block (2 rows): recompute ctx = relu(x@Wc+bc) redundantly (~128 MAC/thr),
// then s_i = P_i@W{q,k} + b{q,k} + ctx (two rows share each W column load),
// then qp_i = s_i@W1a + b1 / kp_i = s_i@W1b, written as f16.
// Threads 0..127 = q-side (h=t), 128..255 = k-side (h=t-128).
__global__ __launch_bounds__(256) void proj_kernel(
    const float* __restrict__ x, const float* __restrict__ P,
    const float* __restrict__ Wq, const float* __restrict__ bq,
    const float* __restrict__ Wk, const float* __restrict__ bk,
    const float* __restrict__ Wc, const float* __restrict__ bc,
    const float* __restrict__ W1, const float* __restrict__ b1,
    half_t* __restrict__ qh, half_t* __restrict__ kh) {
    __shared__ __align__(16) float xs[E];        // next-state embedding
    __shared__ __align__(16) float p_s[2 * E];   // 2 P rows
    __shared__ float pc[2 * H];                  // ctx partials
    __shared__ float aq[H], ak[H];               // bq+ctx, bk+ctx
    __shared__ float sv[2][2 * H];               // s vectors: [row][q:0..127 | k:128..255]

    int b = blockIdx.x, t = threadIdx.x;
    int i0 = b * 2;
    if (t < 64) ((float4*)xs)[t] = ((const float4*)x)[t];
    else if (t < 192) ((float4*)p_s)[t - 64] = ((const float4*)(P + i0 * E))[t - 64];
    __syncthreads();

    int h = t & (H - 1);
    int c = t >> 7;  // 0 = q-side, 1 = k-side
    // ctx partials: side c covers e in [c*128, c*128+128)
    {
        float p = 0.f;
#pragma unroll 8
        for (int e = c * H; e < c * H + H; ++e) p += xs[e] * Wc[e * H + h];
        pc[c * H + h] = p;
    }
    __syncthreads();
    if (t < H) {
        float ctxv = fmaxf(pc[t] + pc[H + t] + bc[t], 0.f);
        aq[t] = bq[t] + ctxv;
        ak[t] = bk[t] + ctxv;
    }
    __syncthreads();

    // s_i = P_i @ W + (b + ctx); both rows share each W column load
    {
        const float* W = c ? Wk : Wq;
        float a0 = c ? ak[h] : aq[h];
        float a1 = a0;
        for (int e = 0; e < E; e += 8) {
            float m0 = W[(e + 0) * H + h];
            float m1 = W[(e + 1) * H + h];
            float m2 = W[(e + 2) * H + h];
            float m3 = W[(e + 3) * H + h];
            float m4 = W[(e + 4) * H + h];
            float m5 = W[(e + 5) * H + h];
            float m6 = W[(e + 6) * H + h];
            float m7 = W[(e + 7) * H + h];
            float4 p0a = *(const float4*)&p_s[0 * E + e];
            float4 p0b = *(const float4*)&p_s[0 * E + e + 4];
            float4 p1a = *(const float4*)&p_s[1 * E + e];
            float4 p1b = *(const float4*)&p_s[1 * E + e + 4];
            a0 += p0a.x * m0 + p0a.y * m1 + p0a.z * m2 + p0a.w * m3
                + p0b.x * m4 + p0b.y * m5 + p0b.z * m6 + p0b.w * m7;
            a1 += p1a.x * m0 + p1a.y * m1 + p1a.z * m2 + p1a.w * m3
                + p1b.x * m4 + p1b.y * m5 + p1b.z * m6 + p1b.w * m7;
        }
        sv[0][c * H + h] = a0;
        sv[1][c * H + h] = a1;
    }
    __syncthreads();

    // qp_i = s_i @ W1a + b1 (q-side) ; kp_i = s_i @ W1b (k-side).
    // sv reads are wave-broadcast (same addr across lanes).
    {
        const float* W1c = W1 + c * H * H;
        const float* S0 = &sv[0][c * H];
        const float* S1 = &sv[1][c * H];
        float a0 = c ? 0.f : b1[h];
        float a1 = a0;
        for (int r = 0; r < H; r += 8) {
            float w0 = W1c[(r + 0) * H + h];
            float w1 = W1c[(r + 1) * H + h];
            float w2 = W1c[(r + 2) * H + h];
            float w3 = W1c[(r + 3) * H + h];
            float w4 = W1c[(r + 4) * H + h];
            float w5 = W1c[(r + 5) * H + h];
            float w6 = W1c[(r + 6) * H + h];
            float w7 = W1c[(r + 7) * H + h];
            a0 += S0[r + 0] * w0 + S0[r + 1] * w1 + S0[r + 2] * w2 + S0[r + 3] * w3
                + S0[r + 4] * w4 + S0[r + 5] * w5 + S0[r + 6] * w6 + S0[r + 7] * w7;
            a1 += S1[r + 0] * w0 + S1[r + 1] * w1 + S1[r + 2] * w2 + S1[r + 3] * w3
                + S1[r + 4] * w4 + S1[r + 5] * w5 + S1[r + 6] * w6 + S1[r + 7] * w7;
        }
        half_t* O = c ? kh : qh;
        O[(i0 + 0) * H + h] = (half_t)a0;
        O[(i0 + 1) * H + h] = (half_t)a1;
    }
}

// pair: exact triangular tiling. 528 blocks, one 32x32 (bi<=bj) tile each.
// Per thread: 4 (i,j) pairs; f16 LDS + fdot2. (Unchanged, harness-verified.)
#define QSTR 136  // halves; 272 B row stride -> conflict-free b128
__global__ __launch_bounds__(256) void pair_kernel(
    const half_t* __restrict__ qh, const half_t* __restrict__ kh,
    const float* __restrict__ W2, const float* __restrict__ b2,
    float* __restrict__ out) {
    int tid = blockIdx.x;
    int bi = (int)((65.0f - sqrtf(4225.0f - 8.0f * (float)tid)) * 0.5f);
    while (bi > 0 && tid < 32 * bi - bi * (bi - 1) / 2) --bi;
    while (tid >= 32 * (bi + 1) - (bi + 1) * bi / 2) ++bi;
    int bj = bi + (tid - (32 * bi - bi * (bi - 1) / 2));

    __shared__ __align__(16) half_t qs[32][QSTR];
    __shared__ __align__(16) half_t ks[32][QSTR];
    __shared__ __align__(16) half_t w2s[H];

    int t = threadIdx.x;
    if (t < H) w2s[t] = (half_t)W2[t];

    const float4* qh4 = (const float4*)(qh + bi * 32 * H);
    const float4* kh4 = (const float4*)(kh + bj * 32 * H);
#pragma unroll
    for (int v = 0; v < 2; ++v) {
        int idx = v * 256 + t;  // 0..511 : 32 rows x 16 float4
        int r = idx >> 4, c = idx & 15;
        float4 q = qh4[idx];
        float4 k = kh4[idx];
        *(float4*)&qs[r][c * 8] = q;
        *(float4*)&ks[r][c * 8] = k;
    }
    __syncthreads();

    int jj  = t & 31;  // k row within tile
    int ti0 = t >> 5;  // q rows ti0, ti0+8, ti0+16, ti0+24
    float b2v = b2[0];
    float acc[4];
#pragma unroll
    for (int u = 0; u < 4; ++u) acc[u] = b2v;

    for (int h8 = 0; h8 < 16; ++h8) {
        float4 wf = *(const float4*)&w2s[h8 * 8];
        float4 kv = *(const float4*)&ks[jj][h8 * 8];
        const hv2* wp = (const hv2*)&wf;
        const hv2* kp2 = (const hv2*)&kv;
#pragma unroll
        for (int u = 0; u < 4; ++u) {
            float4 qf = *(const float4*)&qs[ti0 + u * 8][h8 * 8];
            const hv2* qp2 = (const hv2*)&qf;
#pragma unroll
            for (int s = 0; s < 4; ++s) {
                hv2 sa = relu_add2(qp2[s], kp2[s]);
                acc[u] = dot2_acc(sa, wp[s], acc[u]);
            }
        }
    }

#pragma unroll
    for (int u = 0; u < 4; ++u) {
        int i = bi * 32 + ti0 + u * 8;
        int j = bj * 32 + jj;
        if (j > i) {
            int base = i * (2 * N - i - 1) / 2;
            out[base + (j - i - 1)] = acc[u];
        }
    }
}

extern "C" void kernel_launch(void* const* d_in, const int* in_sizes, int n_in,
                              void* d_out, int out_size, void* d_ws, size_t ws_size,
                              hipStream_t stream) {
    const float* x  = (const float*)d_in[0];
    const float* P  = (const float*)d_in[1];
    const float* Wq = (const float*)d_in[2];
    const float* bq = (const float*)d_in[3];
    const float* Wk = (const float*)d_in[4];
    const float* bk = (const float*)d_in[5];
    const float* Wc = (const float*)d_in[6];
    const float* bc = (const float*)d_in[7];
    const float* W1 = (const float*)d_in[8];
    const float* b1 = (const float*)d_in[9];
    const float* W2 = (const float*)d_in[10];
    const float* b2 = (const float*)d_in[11];
    float* out = (float*)d_out;

    half_t* qh = (half_t*)d_ws;        // 1024*128 halves
    half_t* kh = qh + N * H;           // 1024*128 halves

    proj_kernel<<<N / 2, 256, 0, stream>>>(x, P, Wq, bq, Wk, bk, Wc, bc, W1, b1,
                                           qh, kh);
    pair_kernel<<<528, 256, 0, stream>>>(qh, kh, W2, b2, out);
}